// Round 4
// baseline (128.391 us; speedup 1.0000x reference)
//
#include <hip/hip_runtime.h>
#include <math.h>

// SSM diagonal scan, fused chunked-scan, v2 (low register pressure).
//   reference: h_t = dA ⊙ h_{t-1} + dB·x_t ;  y_t = <C, h_t>
//   dt=exp(log_dt), A=exp(A_log), dA=exp(dt*A), dB=dt*B  (time-invariant).
// Algebra: u_n(t) = dA_n·u_n(t-1) + x_t  (1 FMA/state/step), y_t = Σ_n dBC_n·u_n,
//   dBC = dt·B·C. Carries combine in u-space with dA^CL = exp(CL·dt·A).
//
// Round-3 postmortem: keeping xb[32] live across the combine barrier (plus 32
// 64-bit load addresses: 8KB stride > 13-bit offset imm) pushed VGPRs to the
// 128 cap and serialized load issue -> kernel ~35us vs ~11us HBM floor.
// v2: pass 2 RE-READS x from cache instead (block tile = 64KB, just read ->
// L2-resident; extra HBM ~0, extra L2 time ~1us overlapped). Both passes use a
// PF=8 prefetch ring -> ~70 VGPRs, 2 blocks/CU = 16 waves/CU, in-flight
// loads/CU = 16 waves × 8 × 256B = 32KB >> latency·BW product -> BW-bound.
//
// Mapping: block = 512 thr = 32 d × 16 chunks (CL=32); grid = 64×8 = 512 blocks.
// LDS: only the 34.8KB chunk-state exchange buffer (stride-17 float4 padding).

#define SSM_BATCH 8
#define SSM_SEQ 512
#define SSM_D 2048
#define SSM_N 16
#define NC 16          // chunks per sequence
#define CL 32          // chunk length = SEQ/NC
#define DPB 32         // d-channels per block
#define PF 8           // prefetch ring depth

typedef float float4v __attribute__((ext_vector_type(4)));

static __device__ inline float4v fma4(float4v a, float4v b, float4v c) {
    return (float4v){fmaf(a.x, b.x, c.x), fmaf(a.y, b.y, c.y),
                     fmaf(a.z, b.z, c.z), fmaf(a.w, b.w, c.w)};
}
static __device__ inline float4v exp4(float4v v) {
    return (float4v){expf(v.x), expf(v.y), expf(v.z), expf(v.w)};
}

__global__ __launch_bounds__(512, 6) void ssm_fused2(
    const float* __restrict__ x, const float* __restrict__ A_log,
    const float* __restrict__ Bm, const float* __restrict__ Cm,
    const float* __restrict__ log_dt, float* __restrict__ out)
{
    const int tid = threadIdx.x;
    const int dl  = tid & (DPB - 1);   // channel within block
    const int c   = tid >> 5;          // chunk index 0..15
    const int d   = blockIdx.x * DPB + dl;
    const int b   = blockIdx.y;

    __shared__ float4v S4[DPB * 4 * 17];   // 34816 B

    const size_t xoff = ((size_t)b * SSM_SEQ + c * CL) * SSM_D + d;
    const float* xp = x + xoff;

    // ---- per-channel params ----
    const float dt = expf(log_dt[d]);
    float4v dA[4];
    #pragma unroll
    for (int j = 0; j < 4; ++j) {
        float4v al = *(const float4v*)(A_log + d * SSM_N + 4 * j);
        dA[j] = exp4(dt * exp4(al));
    }

    // ---- pass 1: chunk-local scan from 0 -> U_c (PF-ring over x) ----
    float4v u[4];
    #pragma unroll
    for (int j = 0; j < 4; ++j) u[j] = (float4v)0.f;
    {
        float xb[PF];
        #pragma unroll
        for (int i = 0; i < PF; ++i) xb[i] = xp[(size_t)i * SSM_D];
        #pragma unroll
        for (int t0 = 0; t0 < CL; t0 += PF) {
            float xn[PF];
            if (t0 + PF < CL) {
                #pragma unroll
                for (int i = 0; i < PF; ++i) xn[i] = xp[(size_t)(t0 + PF + i) * SSM_D];
            }
            #pragma unroll
            for (int i = 0; i < PF; ++i) {
                const float xv = xb[i];
                const float4v xs = {xv, xv, xv, xv};
                #pragma unroll
                for (int j = 0; j < 4; ++j) u[j] = fma4(dA[j], u[j], xs);
            }
            #pragma unroll
            for (int i = 0; i < PF; ++i) xb[i] = xn[i];
        }
    }
    #pragma unroll
    for (int j = 0; j < 4; ++j) S4[(dl * 4 + j) * 17 + c] = u[j];
    __syncthreads();

    // ---- combine: 128 chains (32 d × 4 state-groups), serial over 16 chunks ----
    if (tid < DPB * 4) {
        const int cdl = tid >> 2, g = tid & 3;
        const int dd  = blockIdx.x * DPB + cdl;
        const float dt2 = expf(log_dt[dd]);
        float4v al = *(const float4v*)(A_log + dd * SSM_N + 4 * g);
        float4v dAL = exp4(((float)CL * dt2) * exp4(al));   // dA^CL
        float4v H = (float4v)0.f;
        float4v* row = &S4[(cdl * 4 + g) * 17];
        #pragma unroll
        for (int cc = 0; cc < NC; ++cc) {
            float4v s = row[cc];
            row[cc] = H;               // exclusive prefix = carry-in for chunk cc
            H = fma4(dAL, H, s);
        }
    }
    __syncthreads();

    // ---- pass 2: rescan from carry, x re-read (L2-warm), emit y ----
    float4v dBC[4];
    #pragma unroll
    for (int j = 0; j < 4; ++j) {
        float4v bv = *(const float4v*)(Bm + d * SSM_N + 4 * j);
        float4v cv = *(const float4v*)(Cm + d * SSM_N + 4 * j);
        dBC[j] = (dt * bv) * cv;
        u[j] = S4[(dl * 4 + j) * 17 + c];   // carry-in
    }

    float* op = out + xoff;
    {
        float xb[PF];
        #pragma unroll
        for (int i = 0; i < PF; ++i) xb[i] = xp[(size_t)i * SSM_D];
        #pragma unroll
        for (int t0 = 0; t0 < CL; t0 += PF) {
            float xn[PF];
            if (t0 + PF < CL) {
                #pragma unroll
                for (int i = 0; i < PF; ++i) xn[i] = xp[(size_t)(t0 + PF + i) * SSM_D];
            }
            #pragma unroll
            for (int i = 0; i < PF; ++i) {
                const float xv = xb[i];
                const float4v xs = {xv, xv, xv, xv};
                #pragma unroll
                for (int j = 0; j < 4; ++j) u[j] = fma4(dA[j], u[j], xs);
                float4v p = dBC[0] * u[0];
                p = fma4(dBC[1], u[1], p);
                p = fma4(dBC[2], u[2], p);
                p = fma4(dBC[3], u[3], p);
                op[(size_t)(t0 + i) * SSM_D] = (p.x + p.y) + (p.z + p.w);
            }
            #pragma unroll
            for (int i = 0; i < PF; ++i) xb[i] = xn[i];
        }
    }
}

extern "C" void kernel_launch(void* const* d_in, const int* in_sizes, int n_in,
                              void* d_out, int out_size, void* d_ws, size_t ws_size,
                              hipStream_t stream) {
    const float* x      = (const float*)d_in[0];
    const float* A_log  = (const float*)d_in[1];
    const float* B      = (const float*)d_in[2];
    const float* C      = (const float*)d_in[3];
    const float* log_dt = (const float*)d_in[4];
    float* out = (float*)d_out;

    dim3 grid(SSM_D / DPB, SSM_BATCH);   // 64 x 8 = 512 blocks, 2 blocks/CU
    ssm_fused2<<<grid, DPB * NC, 0, stream>>>(x, A_log, B, C, log_dt, out);
}

// Round 5
// 100.791 us; speedup vs baseline: 1.2738x; 1.2738x over previous
//
#include <hip/hip_runtime.h>
#include <math.h>

// SSM diagonal scan, fused chunked-scan v3 (256B-granule-clean layout).
//   reference: h_t = dA ⊙ h_{t-1} + dB·x_t ;  y_t = <C, h_t>
//   dt=exp(log_dt), A=exp(A_log), dA=exp(dt*A), dB=dt*B  (time-invariant).
// Algebra: u_n(t) = dA_n·u_n(t-1) + x_t, y_t = Σ_n dBC_n·u_n with dBC = dt·B·C.
// Carries combine in u-space with dA^CL = exp(CL·dt·A).
//
// Round-4 postmortem: v2 (32-d strips per block, half-wave = 128B segments) showed
// WRITE_SIZE 118 MB for a 33.5 MB output (3.6x write amplification) and FETCH 70 MB
// (x from HBM twice — L2 thrashed). Round-1's 64-d-wide blocks had WRITE == output
// exactly. Conclusion: 256B memory granules straddling two blocks (different L2s)
// cause partial-granule RMW. Fix = layout, not ILP:
//   wave = 64 CONSECUTIVE d, one chunk  -> every x read / y write is a single
//   fully-dirty 256B-aligned segment per wave-instruction; 64-d strips per block.
// Block = 1024 thr = 64 d × 16 chunks (CL=32); grid = 32×8 = 256 blocks = 1/CU
// = 16 waves/CU. xb[32] stays in registers across the combine barrier (no x
// re-read; v2 proved the re-read costs 33 MB of HBM). ~92 VGPRs < 128 cap.
// Ideal traffic 67 MB -> ~11 us; predict kernel 12-16 us.

#define SSM_BATCH 8
#define SSM_SEQ 512
#define SSM_D 2048
#define SSM_N 16
#define NC 16          // chunks per sequence (one wave each)
#define CL 32          // chunk length = SEQ/NC
#define DPB 64         // d-channels per block == lanes per wave

typedef float float4v __attribute__((ext_vector_type(4)));

static __device__ inline float4v fma4(float4v a, float4v b, float4v c) {
    return (float4v){fmaf(a.x, b.x, c.x), fmaf(a.y, b.y, c.y),
                     fmaf(a.z, b.z, c.z), fmaf(a.w, b.w, c.w)};
}
static __device__ inline float4v exp4(float4v v) {
    return (float4v){expf(v.x), expf(v.y), expf(v.z), expf(v.w)};
}

__global__ __launch_bounds__(1024, 4) void ssm_fused3(
    const float* __restrict__ x, const float* __restrict__ A_log,
    const float* __restrict__ Bm, const float* __restrict__ Cm,
    const float* __restrict__ log_dt, float* __restrict__ out)
{
    const int tid = threadIdx.x;
    const int dl  = tid & (DPB - 1);   // lane = channel within block (64-wide)
    const int c   = tid >> 6;          // chunk index 0..15 (= wave id)
    const int d   = blockIdx.x * DPB + dl;
    const int b   = blockIdx.y;

    // [DPB*4 chains][stride 17 float4] — +1 pad breaks power-of-2 bank stride.
    __shared__ float4v S4[DPB * 4 * 17];   // 69632 B

    const size_t xoff = ((size_t)b * SSM_SEQ + c * CL) * SSM_D + d;
    const float* xp = x + xoff;

    // ---- issue all 32 x loads first (scan-independent -> max MLP) ----
    float xb[CL];
    #pragma unroll
    for (int t = 0; t < CL; ++t) xb[t] = xp[(size_t)t * SSM_D];

    // ---- per-channel params (exp chain overlaps the loads) ----
    const float dt = expf(log_dt[d]);
    float4v dA[4];
    #pragma unroll
    for (int j = 0; j < 4; ++j) {
        float4v al = *(const float4v*)(A_log + d * SSM_N + 4 * j);
        dA[j] = exp4(dt * exp4(al));
    }

    // ---- pass 1: chunk-local scan from 0 -> U_c ----
    float4v u[4];
    #pragma unroll
    for (int j = 0; j < 4; ++j) u[j] = (float4v)0.f;
    #pragma unroll
    for (int t = 0; t < CL; ++t) {
        const float xv = xb[t];
        const float4v xs = {xv, xv, xv, xv};
        #pragma unroll
        for (int j = 0; j < 4; ++j) u[j] = fma4(dA[j], u[j], xs);
    }
    #pragma unroll
    for (int j = 0; j < 4; ++j) S4[(dl * 4 + j) * 17 + c] = u[j];
    __syncthreads();

    // ---- combine: 256 chains (64 d × 4 state-groups), serial over 16 chunks ----
    if (tid < DPB * 4) {
        const int cdl = tid >> 2, g = tid & 3;
        const int dd  = blockIdx.x * DPB + cdl;
        const float dt2 = expf(log_dt[dd]);
        float4v al = *(const float4v*)(A_log + dd * SSM_N + 4 * g);
        float4v dAL = exp4(((float)CL * dt2) * exp4(al));   // dA^CL
        float4v H = (float4v)0.f;
        float4v* row = &S4[(cdl * 4 + g) * 17];
        #pragma unroll
        for (int cc = 0; cc < NC; ++cc) {
            float4v s = row[cc];
            row[cc] = H;               // exclusive prefix = carry-in for chunk cc
            H = fma4(dAL, H, s);
        }
    }
    __syncthreads();

    // ---- pass 2: rescan from carry, reuse x still in registers, emit y ----
    float4v dBC[4];
    #pragma unroll
    for (int j = 0; j < 4; ++j) {
        float4v bv = *(const float4v*)(Bm + d * SSM_N + 4 * j);
        float4v cv = *(const float4v*)(Cm + d * SSM_N + 4 * j);
        dBC[j] = (dt * bv) * cv;
        u[j] = S4[(dl * 4 + j) * 17 + c];   // carry-in
    }

    float* op = out + xoff;
    #pragma unroll
    for (int t = 0; t < CL; ++t) {
        const float xv = xb[t];
        const float4v xs = {xv, xv, xv, xv};
        #pragma unroll
        for (int j = 0; j < 4; ++j) u[j] = fma4(dA[j], u[j], xs);
        float4v p = dBC[0] * u[0];
        p = fma4(dBC[1], u[1], p);
        p = fma4(dBC[2], u[2], p);
        p = fma4(dBC[3], u[3], p);
        op[(size_t)t * SSM_D] = (p.x + p.y) + (p.z + p.w);
    }
}

extern "C" void kernel_launch(void* const* d_in, const int* in_sizes, int n_in,
                              void* d_out, int out_size, void* d_ws, size_t ws_size,
                              hipStream_t stream) {
    const float* x      = (const float*)d_in[0];
    const float* A_log  = (const float*)d_in[1];
    const float* B      = (const float*)d_in[2];
    const float* C      = (const float*)d_in[3];
    const float* log_dt = (const float*)d_in[4];
    float* out = (float*)d_out;

    dim3 grid(SSM_D / DPB, SSM_BATCH);   // 32 x 8 = 256 blocks, 1 block/CU
    ssm_fused3<<<grid, DPB * NC, 0, stream>>>(x, A_log, B, C, log_dt, out);
}